// Round 1
// baseline (2915.255 us; speedup 1.0000x reference)
//
#include <hip/hip_runtime.h>

#define N_NODES 100000
#define N_EDGES 1600000
#define F 128

// ---------------------------------------------------------------------------
// Phase 1: edge scatter-add.  agg[dst[e], :] += feature[src[e], :]
// One edge per 32 lanes; each lane handles a float4 (4 feats) -> 512 B/edge.
// unsafeAtomicAdd -> global_atomic_add_f32 (HW fp32 atomic, no CAS loop).
// ---------------------------------------------------------------------------
__global__ __launch_bounds__(256) void gcn_scatter(
    const float* __restrict__ feat,
    const int* __restrict__ src,
    const int* __restrict__ dst,
    float* __restrict__ agg)
{
    const int sub  = threadIdx.x >> 5;     // 8 edges per 256-thread block
    const int lane = threadIdx.x & 31;
    const long long e = (long long)blockIdx.x * 8 + sub;
    if (e >= N_EDGES) return;

    const int s = src[e];
    const int d = dst[e];

    const float4 v = *(const float4*)(feat + (size_t)s * F + lane * 4);
    float* ar = agg + (size_t)d * F + lane * 4;
    unsafeAtomicAdd(ar + 0, v.x);
    unsafeAtomicAdd(ar + 1, v.y);
    unsafeAtomicAdd(ar + 2, v.z);
    unsafeAtomicAdd(ar + 3, v.w);
}

// ---------------------------------------------------------------------------
// Phase 2: out = relu(agg @ W^T + b), IN-PLACE on the agg buffer.
// Each block owns 64 rows: stages its rows + all of W into LDS (read happens
// strictly before any write to those rows), then register-tiled fp32 FMA.
//
// Thread layout: 256 threads, tx = tid&15 (cols j = tx + 16m, m<8 -> strided
// so Wlds float4 reads are 2-way-bank at pad 132 = free), ty = tid>>4
// (rows r0 = ty*4 .. +3).  32 outputs/thread, 128 FMA per k-chunk of 4.
// LDS: Wlds 128x132 (67.6 KB) + At 64x132 (33.8 KB) = 101 KB -> 1 block/CU.
// ---------------------------------------------------------------------------
#define GR  64
#define LDW 132

__global__ __launch_bounds__(256) void gcn_gemm_relu(
    float* __restrict__ agg_out,          // in: agg rows, out: relu(agg@W^T+b)
    const float* __restrict__ W,          // [F][F] row-major, W[j][k]
    const float* __restrict__ b)          // [F]
{
    __shared__ float Wlds[F][LDW];
    __shared__ float At[GR][LDW];

    const int tid = threadIdx.x;
    const long long row0 = (long long)blockIdx.x * GR;

    // Stage W (natural layout, scalar copy: coalesced global, conflict-free LDS)
    #pragma unroll
    for (int i = 0; i < 64; ++i) {
        const int e = tid + i * 256;      // [0, 16384)
        Wlds[e >> 7][e & 127] = W[e];
    }
    // Stage this block's 64 agg rows
    #pragma unroll
    for (int i = 0; i < 32; ++i) {
        const int e = tid + i * 256;      // [0, 8192)
        const int r = e >> 7, k = e & 127;
        const long long gr = row0 + r;
        At[r][k] = (gr < N_NODES) ? agg_out[gr * F + k] : 0.0f;
    }
    __syncthreads();

    const int tx = tid & 15;
    const int ty = tid >> 4;
    const int r0 = ty * 4;

    float acc[4][8];
    #pragma unroll
    for (int r = 0; r < 4; ++r)
        #pragma unroll
        for (int m = 0; m < 8; ++m) acc[r][m] = 0.0f;

    for (int k0 = 0; k0 < F; k0 += 4) {
        float4 a[4], w[8];
        #pragma unroll
        for (int r = 0; r < 4; ++r)
            a[r] = *(const float4*)&At[r0 + r][k0];
        #pragma unroll
        for (int m = 0; m < 8; ++m)
            w[m] = *(const float4*)&Wlds[tx + 16 * m][k0];
        #pragma unroll
        for (int r = 0; r < 4; ++r)
            #pragma unroll
            for (int m = 0; m < 8; ++m)
                acc[r][m] += a[r].x * w[m].x + a[r].y * w[m].y
                           + a[r].z * w[m].z + a[r].w * w[m].w;
    }

    float bias[8];
    #pragma unroll
    for (int m = 0; m < 8; ++m) bias[m] = b[tx + 16 * m];

    __syncthreads();   // all reads of this block's rows done before overwrite

    #pragma unroll
    for (int r = 0; r < 4; ++r) {
        const long long gr = row0 + r0 + r;
        if (gr < N_NODES) {
            float* orow = agg_out + gr * F;
            #pragma unroll
            for (int m = 0; m < 8; ++m) {
                const float v = acc[r][m] + bias[m];
                orow[tx + 16 * m] = v > 0.0f ? v : 0.0f;
            }
        }
    }
}

extern "C" void kernel_launch(void* const* d_in, const int* in_sizes, int n_in,
                              void* d_out, int out_size, void* d_ws, size_t ws_size,
                              hipStream_t stream) {
    const float* feat = (const float*)d_in[0];
    const int*   src  = (const int*)d_in[1];
    const int*   dst  = (const int*)d_in[2];
    const float* W    = (const float*)d_in[3];
    const float* b    = (const float*)d_in[4];
    float* out = (float*)d_out;

    // agg accumulates directly in d_out (re-poisoned each launch -> zero it)
    hipMemsetAsync(out, 0, (size_t)N_NODES * F * sizeof(float), stream);

    const int scatter_blocks = N_EDGES / 8;            // 8 edges per block
    gcn_scatter<<<scatter_blocks, 256, 0, stream>>>(feat, src, dst, out);

    const int gemm_blocks = (N_NODES + GR - 1) / GR;   // 1563
    gcn_gemm_relu<<<gemm_blocks, 256, 0, stream>>>(out, W, b);
}

// Round 2
// 527.199 us; speedup vs baseline: 5.5297x; 5.5297x over previous
//
#include <hip/hip_runtime.h>

#define N_NODES 100000
#define N_EDGES 1600000
#define F 128

// ============================ CSR build =====================================
// ws layout: deg[N] | start[N] | cursor[N] | gcur[4] | edge_src[E]

__global__ __launch_bounds__(256) void gcn_hist(
    const int* __restrict__ dst, int* __restrict__ deg)
{
    const int e = blockIdx.x * 256 + threadIdx.x;
    if (e < N_EDGES) atomicAdd(&deg[dst[e]], 1);
}

// Per-block inclusive scan of 256 degrees + one global atomic per block to
// allocate a contiguous segment range. Node segments land in arbitrary order
// (block scheduling), which is fine: gather only needs [start, start+deg).
__global__ __launch_bounds__(256) void gcn_alloc(
    const int* __restrict__ deg, int* __restrict__ start,
    int* __restrict__ cursor, int* __restrict__ gcur)
{
    __shared__ int s[256];
    __shared__ int base;
    const int tid = threadIdx.x;
    const int n = blockIdx.x * 256 + tid;
    const int d = (n < N_NODES) ? deg[n] : 0;
    s[tid] = d;
    __syncthreads();
    #pragma unroll
    for (int off = 1; off < 256; off <<= 1) {
        const int t = (tid >= off) ? s[tid - off] : 0;
        __syncthreads();
        s[tid] += t;
        __syncthreads();
    }
    if (tid == 255) base = atomicAdd(gcur, s[255]);
    __syncthreads();
    if (n < N_NODES) {
        const int st = base + s[tid] - d;   // exclusive position
        start[n]  = st;
        cursor[n] = st;
    }
}

__global__ __launch_bounds__(256) void gcn_place(
    const int* __restrict__ src, const int* __restrict__ dst,
    int* __restrict__ cursor, int* __restrict__ edge_src)
{
    const int e = blockIdx.x * 256 + threadIdx.x;
    if (e < N_EDGES) {
        const int pos = atomicAdd(&cursor[dst[e]], 1);
        edge_src[pos] = src[e];
    }
}

// ============================ gather ========================================
// 32 lanes per node (float4/lane = 128 feats), 8 nodes per block.
// 2-deep unroll -> 2 outstanding feat-row loads per group (MLP).
__global__ __launch_bounds__(256) void gcn_gather(
    const float* __restrict__ feat,
    const int* __restrict__ start, const int* __restrict__ deg,
    const int* __restrict__ edge_src,
    float* __restrict__ agg)
{
    const int g    = threadIdx.x >> 5;
    const int lane = threadIdx.x & 31;
    const int n    = blockIdx.x * 8 + g;          // grid = 12500 exact
    const int st   = start[n];
    const int de   = deg[n];
    const float* fb = feat + (size_t)lane * 4;

    float4 acc0 = {0.f, 0.f, 0.f, 0.f};
    float4 acc1 = {0.f, 0.f, 0.f, 0.f};
    int i = 0;
    for (; i + 1 < de; i += 2) {
        const int s0 = edge_src[st + i];
        const int s1 = edge_src[st + i + 1];
        const float4 v0 = *(const float4*)(fb + (size_t)s0 * F);
        const float4 v1 = *(const float4*)(fb + (size_t)s1 * F);
        acc0.x += v0.x; acc0.y += v0.y; acc0.z += v0.z; acc0.w += v0.w;
        acc1.x += v1.x; acc1.y += v1.y; acc1.z += v1.z; acc1.w += v1.w;
    }
    if (i < de) {
        const int s0 = edge_src[st + i];
        const float4 v0 = *(const float4*)(fb + (size_t)s0 * F);
        acc0.x += v0.x; acc0.y += v0.y; acc0.z += v0.z; acc0.w += v0.w;
    }
    acc0.x += acc1.x; acc0.y += acc1.y; acc0.z += acc1.z; acc0.w += acc1.w;
    *(float4*)(agg + (size_t)n * F + lane * 4) = acc0;
}

// ==================== fallback: atomic scatter (ws too small) ===============
__global__ __launch_bounds__(256) void gcn_scatter(
    const float* __restrict__ feat,
    const int* __restrict__ src, const int* __restrict__ dst,
    float* __restrict__ agg)
{
    const int sub  = threadIdx.x >> 5;
    const int lane = threadIdx.x & 31;
    const long long e = (long long)blockIdx.x * 8 + sub;
    if (e >= N_EDGES) return;
    const int s = src[e], d = dst[e];
    const float4 v = *(const float4*)(feat + (size_t)s * F + lane * 4);
    float* ar = agg + (size_t)d * F + lane * 4;
    unsafeAtomicAdd(ar + 0, v.x);
    unsafeAtomicAdd(ar + 1, v.y);
    unsafeAtomicAdd(ar + 2, v.z);
    unsafeAtomicAdd(ar + 3, v.w);
}

// ============================ GEMM + bias + ReLU ============================
#define GR  64
#define LDW 132

__global__ __launch_bounds__(256) void gcn_gemm_relu(
    float* __restrict__ agg_out,
    const float* __restrict__ W, const float* __restrict__ b)
{
    __shared__ float Wlds[F][LDW];
    __shared__ float At[GR][LDW];

    const int tid = threadIdx.x;
    const long long row0 = (long long)blockIdx.x * GR;

    #pragma unroll
    for (int i = 0; i < 64; ++i) {
        const int e = tid + i * 256;
        Wlds[e >> 7][e & 127] = W[e];
    }
    #pragma unroll
    for (int i = 0; i < 32; ++i) {
        const int e = tid + i * 256;
        const int r = e >> 7, k = e & 127;
        const long long gr = row0 + r;
        At[r][k] = (gr < N_NODES) ? agg_out[gr * F + k] : 0.0f;
    }
    __syncthreads();

    const int tx = tid & 15;
    const int ty = tid >> 4;
    const int r0 = ty * 4;

    float acc[4][8];
    #pragma unroll
    for (int r = 0; r < 4; ++r)
        #pragma unroll
        for (int m = 0; m < 8; ++m) acc[r][m] = 0.0f;

    for (int k0 = 0; k0 < F; k0 += 4) {
        float4 a[4], w[8];
        #pragma unroll
        for (int r = 0; r < 4; ++r)
            a[r] = *(const float4*)&At[r0 + r][k0];
        #pragma unroll
        for (int m = 0; m < 8; ++m)
            w[m] = *(const float4*)&Wlds[tx + 16 * m][k0];
        #pragma unroll
        for (int r = 0; r < 4; ++r)
            #pragma unroll
            for (int m = 0; m < 8; ++m)
                acc[r][m] += a[r].x * w[m].x + a[r].y * w[m].y
                           + a[r].z * w[m].z + a[r].w * w[m].w;
    }

    float bias[8];
    #pragma unroll
    for (int m = 0; m < 8; ++m) bias[m] = b[tx + 16 * m];

    __syncthreads();

    #pragma unroll
    for (int r = 0; r < 4; ++r) {
        const long long gr = row0 + r0 + r;
        if (gr < N_NODES) {
            float* orow = agg_out + gr * F;
            #pragma unroll
            for (int m = 0; m < 8; ++m) {
                const float v = acc[r][m] + bias[m];
                orow[tx + 16 * m] = v > 0.0f ? v : 0.0f;
            }
        }
    }
}

extern "C" void kernel_launch(void* const* d_in, const int* in_sizes, int n_in,
                              void* d_out, int out_size, void* d_ws, size_t ws_size,
                              hipStream_t stream) {
    const float* feat = (const float*)d_in[0];
    const int*   src  = (const int*)d_in[1];
    const int*   dst  = (const int*)d_in[2];
    const float* W    = (const float*)d_in[3];
    const float* b    = (const float*)d_in[4];
    float* out = (float*)d_out;

    const size_t ws_need = ((size_t)3 * N_NODES + 4 + N_EDGES) * sizeof(int);

    if (ws_size >= ws_need) {
        // CSR-gather path (ws_size is constant per session -> same work every call)
        int* deg      = (int*)d_ws;
        int* start    = deg + N_NODES;
        int* cursor   = start + N_NODES;
        int* gcur     = cursor + N_NODES;
        int* edge_src = gcur + 4;

        hipMemsetAsync(deg,  0, (size_t)N_NODES * sizeof(int), stream);
        hipMemsetAsync(gcur, 0, 4 * sizeof(int), stream);

        gcn_hist <<<N_EDGES / 256, 256, 0, stream>>>(dst, deg);
        gcn_alloc<<<(N_NODES + 255) / 256, 256, 0, stream>>>(deg, start, cursor, gcur);
        gcn_place<<<N_EDGES / 256, 256, 0, stream>>>(src, dst, cursor, edge_src);
        gcn_gather<<<N_NODES / 8, 256, 0, stream>>>(feat, start, deg, edge_src, out);
    } else {
        // fallback: atomic scatter directly into d_out
        hipMemsetAsync(out, 0, (size_t)N_NODES * F * sizeof(float), stream);
        gcn_scatter<<<N_EDGES / 8, 256, 0, stream>>>(feat, src, dst, out);
    }

    gcn_gemm_relu<<<(N_NODES + GR - 1) / GR, 256, 0, stream>>>(out, W, b);
}

// Round 3
// 404.469 us; speedup vs baseline: 7.2076x; 1.3034x over previous
//
#include <hip/hip_runtime.h>

#define N_NODES 100000
#define N_EDGES 1600000
#define F 128

typedef __bf16  bf16x8 __attribute__((ext_vector_type(8)));
typedef float   f32x4  __attribute__((ext_vector_type(4)));

__device__ inline unsigned short f32_to_bf16(float f) {
    unsigned u = __builtin_bit_cast(unsigned, f);
    u += 0x7FFFu + ((u >> 16) & 1u);     // round-to-nearest-even (finite inputs)
    return (unsigned short)(u >> 16);
}

// ============================ CSR build =====================================
// ws layout: deg[N] | start[N] | cursor[N] | gcur[4] | edge_src[E] | Wbf[16384]

__global__ __launch_bounds__(256) void gcn_hist(
    const int* __restrict__ dst, int* __restrict__ deg)
{
    const int e = blockIdx.x * 256 + threadIdx.x;
    if (e < N_EDGES) atomicAdd(&deg[dst[e]], 1);
}

__global__ __launch_bounds__(256) void gcn_alloc(
    const int* __restrict__ deg, int* __restrict__ start,
    int* __restrict__ cursor, int* __restrict__ gcur)
{
    __shared__ int s[256];
    __shared__ int base;
    const int tid = threadIdx.x;
    const int n = blockIdx.x * 256 + tid;
    const int d = (n < N_NODES) ? deg[n] : 0;
    s[tid] = d;
    __syncthreads();
    #pragma unroll
    for (int off = 1; off < 256; off <<= 1) {
        const int t = (tid >= off) ? s[tid - off] : 0;
        __syncthreads();
        s[tid] += t;
        __syncthreads();
    }
    if (tid == 255) base = atomicAdd(gcur, s[255]);
    __syncthreads();
    if (n < N_NODES) {
        const int st = base + s[tid] - d;
        start[n]  = st;
        cursor[n] = st;
    }
}

__global__ __launch_bounds__(256) void gcn_place(
    const int* __restrict__ src, const int* __restrict__ dst,
    int* __restrict__ cursor, int* __restrict__ edge_src)
{
    const int e = blockIdx.x * 256 + threadIdx.x;
    if (e < N_EDGES) {
        const int pos = atomicAdd(&cursor[dst[e]], 1);
        edge_src[pos] = src[e];
    }
}

__global__ __launch_bounds__(256) void gcn_wconv(
    const float* __restrict__ W, unsigned short* __restrict__ Wbf)
{
    const int i = blockIdx.x * 256 + threadIdx.x;   // grid covers 16384 exact
    Wbf[i] = f32_to_bf16(W[i]);
}

// ============================ gather (bf16 out) =============================
// 32 lanes per node; fp32 accumulate, bf16 store into the UPPER 256B of the
// node's 512B slot in d_out (lower half written later by the GEMM epilogue).
__global__ __launch_bounds__(256) void gcn_gather_bf16(
    const float* __restrict__ feat,
    const int* __restrict__ start, const int* __restrict__ deg,
    const int* __restrict__ edge_src,
    float* __restrict__ out)
{
    const int g    = threadIdx.x >> 5;
    const int lane = threadIdx.x & 31;
    const int n    = blockIdx.x * 8 + g;          // grid = 12500 exact
    const int st   = start[n];
    const int de   = deg[n];
    const float* fb = feat + (size_t)lane * 4;

    float4 a0 = {0,0,0,0}, a1 = {0,0,0,0}, a2 = {0,0,0,0}, a3 = {0,0,0,0};
    int i = 0;
    for (; i + 3 < de; i += 4) {
        const int s0 = edge_src[st + i];
        const int s1 = edge_src[st + i + 1];
        const int s2 = edge_src[st + i + 2];
        const int s3 = edge_src[st + i + 3];
        const float4 v0 = *(const float4*)(fb + (size_t)s0 * F);
        const float4 v1 = *(const float4*)(fb + (size_t)s1 * F);
        const float4 v2 = *(const float4*)(fb + (size_t)s2 * F);
        const float4 v3 = *(const float4*)(fb + (size_t)s3 * F);
        a0.x += v0.x; a0.y += v0.y; a0.z += v0.z; a0.w += v0.w;
        a1.x += v1.x; a1.y += v1.y; a1.z += v1.z; a1.w += v1.w;
        a2.x += v2.x; a2.y += v2.y; a2.z += v2.z; a2.w += v2.w;
        a3.x += v3.x; a3.y += v3.y; a3.z += v3.z; a3.w += v3.w;
    }
    for (; i < de; ++i) {
        const int s0 = edge_src[st + i];
        const float4 v0 = *(const float4*)(fb + (size_t)s0 * F);
        a0.x += v0.x; a0.y += v0.y; a0.z += v0.z; a0.w += v0.w;
    }
    a0.x += a1.x + a2.x + a3.x;
    a0.y += a1.y + a2.y + a3.y;
    a0.z += a1.z + a2.z + a3.z;
    a0.w += a1.w + a2.w + a3.w;

    uint2 p;
    p.x = (unsigned)f32_to_bf16(a0.x) | ((unsigned)f32_to_bf16(a0.y) << 16);
    p.y = (unsigned)f32_to_bf16(a0.z) | ((unsigned)f32_to_bf16(a0.w) << 16);
    *(uint2*)((char*)out + (size_t)n * 512 + 256 + lane * 8) = p;
}

// ============================ MFMA GEMM + bias + ReLU =======================
// out = relu(agg_bf16 @ W^T + b).  128 rows x 128 cols per block, K=128.
// A staged from each row-slot's upper 256B; block overwrites only its own rows.
#define MT   128
#define LDP  136   // row pitch in ushorts: 16B-aligned chunks, breaks 16-way banks

__global__ __launch_bounds__(256) void gcn_gemm_mfma(
    float* __restrict__ out,
    const unsigned short* __restrict__ Wbf,   // [128][128] bf16, W[n][k]
    const float* __restrict__ b)
{
    __shared__ unsigned short Alds[MT * LDP];
    __shared__ unsigned short Wlds[F * LDP];

    const int tid  = threadIdx.x;
    const int row0 = blockIdx.x * MT;

    // stage W: 2048 chunks of 16B
    #pragma unroll
    for (int i = 0; i < 8; ++i) {
        const int c = tid + i * 256;
        const int r = c >> 4, cc = c & 15;
        *(uint4*)&Wlds[r * LDP + cc * 8] = *(const uint4*)&Wbf[c * 8];
    }
    // stage A: 2048 chunks of 16B from row slots (upper halves)
    #pragma unroll
    for (int i = 0; i < 8; ++i) {
        const int c = tid + i * 256;
        const int r = c >> 4, cc = c & 15;
        int gr = row0 + r; if (gr > N_NODES - 1) gr = N_NODES - 1;
        const uint4 v = *(const uint4*)((const char*)out + (size_t)gr * 512 + 256 + cc * 16);
        *(uint4*)&Alds[r * LDP + cc * 8] = v;
    }
    __syncthreads();

    const int lane = tid & 63;
    const int wv   = tid >> 6;       // wave id: rows [wv*32, wv*32+32)
    const int lr   = lane & 15;
    const int lq   = lane >> 4;

    f32x4 acc[2][8] = {};
    #pragma unroll
    for (int kk = 0; kk < 4; ++kk) {
        bf16x8 a[2], w[8];
        #pragma unroll
        for (int i = 0; i < 2; ++i)
            a[i] = __builtin_bit_cast(bf16x8,
                *(const uint4*)&Alds[(wv * 32 + i * 16 + lr) * LDP + kk * 32 + lq * 8]);
        #pragma unroll
        for (int n = 0; n < 8; ++n)
            w[n] = __builtin_bit_cast(bf16x8,
                *(const uint4*)&Wlds[(n * 16 + lr) * LDP + kk * 32 + lq * 8]);
        #pragma unroll
        for (int i = 0; i < 2; ++i)
            #pragma unroll
            for (int n = 0; n < 8; ++n)
                acc[i][n] = __builtin_amdgcn_mfma_f32_16x16x32_bf16(a[i], w[n], acc[i][n], 0, 0, 0);
    }

    float bias[8];
    #pragma unroll
    for (int n = 0; n < 8; ++n) bias[n] = b[n * 16 + lr];

    // C/D layout: col = lane&15 (within n-frag), row = lq*4 + reg
    #pragma unroll
    for (int i = 0; i < 2; ++i) {
        const int rbase = wv * 32 + i * 16 + lq * 4;
        #pragma unroll
        for (int rg = 0; rg < 4; ++rg) {
            const int gr = row0 + rbase + rg;
            if (gr < N_NODES) {
                float* orow = out + (size_t)gr * F;
                #pragma unroll
                for (int n = 0; n < 8; ++n) {
                    const float v = acc[i][n][rg] + bias[n];
                    orow[n * 16 + lr] = v > 0.0f ? v : 0.0f;
                }
            }
        }
    }
}

// ==================== fallback path (ws too small) ==========================
__global__ __launch_bounds__(256) void gcn_scatter(
    const float* __restrict__ feat,
    const int* __restrict__ src, const int* __restrict__ dst,
    float* __restrict__ agg)
{
    const int sub  = threadIdx.x >> 5;
    const int lane = threadIdx.x & 31;
    const long long e = (long long)blockIdx.x * 8 + sub;
    if (e >= N_EDGES) return;
    const int s = src[e], d = dst[e];
    const float4 v = *(const float4*)(feat + (size_t)s * F + lane * 4);
    float* ar = agg + (size_t)d * F + lane * 4;
    unsafeAtomicAdd(ar + 0, v.x);
    unsafeAtomicAdd(ar + 1, v.y);
    unsafeAtomicAdd(ar + 2, v.z);
    unsafeAtomicAdd(ar + 3, v.w);
}

#define GR  64
#define LDW 132
__global__ __launch_bounds__(256) void gcn_gemm_relu(
    float* __restrict__ agg_out,
    const float* __restrict__ W, const float* __restrict__ b)
{
    __shared__ float Wl[F][LDW];
    __shared__ float At[GR][LDW];
    const int tid = threadIdx.x;
    const long long row0 = (long long)blockIdx.x * GR;
    #pragma unroll
    for (int i = 0; i < 64; ++i) {
        const int e = tid + i * 256;
        Wl[e >> 7][e & 127] = W[e];
    }
    #pragma unroll
    for (int i = 0; i < 32; ++i) {
        const int e = tid + i * 256;
        const int r = e >> 7, k = e & 127;
        const long long gr = row0 + r;
        At[r][k] = (gr < N_NODES) ? agg_out[gr * F + k] : 0.0f;
    }
    __syncthreads();
    const int tx = tid & 15, ty = tid >> 4, r0 = ty * 4;
    float acc[4][8];
    #pragma unroll
    for (int r = 0; r < 4; ++r)
        #pragma unroll
        for (int m = 0; m < 8; ++m) acc[r][m] = 0.0f;
    for (int k0 = 0; k0 < F; k0 += 4) {
        float4 a[4], w[8];
        #pragma unroll
        for (int r = 0; r < 4; ++r) a[r] = *(const float4*)&At[r0 + r][k0];
        #pragma unroll
        for (int m = 0; m < 8; ++m) w[m] = *(const float4*)&Wl[tx + 16 * m][k0];
        #pragma unroll
        for (int r = 0; r < 4; ++r)
            #pragma unroll
            for (int m = 0; m < 8; ++m)
                acc[r][m] += a[r].x * w[m].x + a[r].y * w[m].y
                           + a[r].z * w[m].z + a[r].w * w[m].w;
    }
    float bias[8];
    #pragma unroll
    for (int m = 0; m < 8; ++m) bias[m] = b[tx + 16 * m];
    __syncthreads();
    #pragma unroll
    for (int r = 0; r < 4; ++r) {
        const long long gr = row0 + r0 + r;
        if (gr < N_NODES) {
            float* orow = agg_out + gr * F;
            #pragma unroll
            for (int m = 0; m < 8; ++m) {
                const float v = acc[r][m] + bias[m];
                orow[tx + 16 * m] = v > 0.0f ? v : 0.0f;
            }
        }
    }
}

extern "C" void kernel_launch(void* const* d_in, const int* in_sizes, int n_in,
                              void* d_out, int out_size, void* d_ws, size_t ws_size,
                              hipStream_t stream) {
    const float* feat = (const float*)d_in[0];
    const int*   src  = (const int*)d_in[1];
    const int*   dst  = (const int*)d_in[2];
    const float* W    = (const float*)d_in[3];
    const float* b    = (const float*)d_in[4];
    float* out = (float*)d_out;

    const size_t ws_need = ((size_t)3 * N_NODES + 4 + N_EDGES) * sizeof(int)
                         + (size_t)F * F * sizeof(unsigned short);

    if (ws_size >= ws_need) {
        int* deg      = (int*)d_ws;
        int* start    = deg + N_NODES;
        int* cursor   = start + N_NODES;
        int* gcur     = cursor + N_NODES;
        int* edge_src = gcur + 4;
        unsigned short* Wbf = (unsigned short*)(edge_src + N_EDGES); // 16B aligned

        hipMemsetAsync(deg,  0, (size_t)N_NODES * sizeof(int), stream);
        hipMemsetAsync(gcur, 0, 4 * sizeof(int), stream);

        gcn_wconv <<<F * F / 256, 256, 0, stream>>>(W, Wbf);
        gcn_hist  <<<N_EDGES / 256, 256, 0, stream>>>(dst, deg);
        gcn_alloc <<<(N_NODES + 255) / 256, 256, 0, stream>>>(deg, start, cursor, gcur);
        gcn_place <<<N_EDGES / 256, 256, 0, stream>>>(src, dst, cursor, edge_src);
        gcn_gather_bf16<<<N_NODES / 8, 256, 0, stream>>>(feat, start, deg, edge_src, out);
        gcn_gemm_mfma  <<<(N_NODES + MT - 1) / MT, 256, 0, stream>>>(out, Wbf, b);
    } else {
        hipMemsetAsync(out, 0, (size_t)N_NODES * F * sizeof(float), stream);
        gcn_scatter<<<N_EDGES / 8, 256, 0, stream>>>(feat, src, dst, out);
        gcn_gemm_relu<<<(N_NODES + GR - 1) / GR, 256, 0, stream>>>(out, W, b);
    }
}